// Round 1
// baseline (1612.779 us; speedup 1.0000x reference)
//
#include <hip/hip_runtime.h>

// GCN forward on MI355X.
// h0 = x@w1 + b1            [100000 x 128]
// h1 = spmm(A, h0)          (scatter-atomic baseline)
// h2 = relu(h1)@w2 + b2     [100000 x 64]   (relu fused into gemm2 load)
// out = spmm(A, h2)

constexpr int N_NODES = 100000;
constexpr int IN_F    = 512;
constexpr int HID_F   = 128;
constexpr int N_CLS   = 64;
constexpr int N_EDGES = 1600000;

// ---------------- GEMM1: h0 = x @ w1 + b1 ----------------
// block = 128 threads (one per output feature), 8 rows per block.
// x rows staged in LDS; w1 row (512B) streamed per-k, L2-resident (256 KB).
__global__ __launch_bounds__(128) void gemm1_kernel(
    const float* __restrict__ x, const float* __restrict__ w1,
    const float* __restrict__ b1, float* __restrict__ h0)
{
    __shared__ float xs[8][IN_F];
    const int f = threadIdx.x;          // 0..127
    const int row0 = blockIdx.x * 8;

    // stage 8 rows x 512 floats = 1024 float4, 8 per thread (coalesced)
    const float4* xv  = (const float4*)(x + (size_t)row0 * IN_F);
    float4*       xsv = (float4*)(&xs[0][0]);
#pragma unroll
    for (int i = 0; i < 8; ++i)
        xsv[i * 128 + f] = xv[i * 128 + f];
    __syncthreads();

    float acc[8];
#pragma unroll
    for (int r = 0; r < 8; ++r) acc[r] = b1[f];

#pragma unroll 4
    for (int k = 0; k < IN_F; ++k) {
        float w = w1[k * HID_F + f];    // coalesced, L2-hit after warm
#pragma unroll
        for (int r = 0; r < 8; ++r) acc[r] += xs[r][k] * w;  // LDS broadcast
    }
#pragma unroll
    for (int r = 0; r < 8; ++r)
        h0[(size_t)(row0 + r) * HID_F + f] = acc[r];
}

// ---------------- GEMM2: h2 = relu(h1) @ w2 + b2 ----------------
// block = 64 threads (one per class), 16 rows per block. ReLU fused on load.
__global__ __launch_bounds__(64) void gemm2_kernel(
    const float* __restrict__ h1, const float* __restrict__ w2,
    const float* __restrict__ b2, float* __restrict__ h2)
{
    __shared__ float xs[16][HID_F];
    const int f = threadIdx.x;          // 0..63
    const int row0 = blockIdx.x * 16;

    const float4* xv  = (const float4*)(h1 + (size_t)row0 * HID_F);
    float4*       xsv = (float4*)(&xs[0][0]);
#pragma unroll
    for (int i = 0; i < 8; ++i) {
        float4 t = xv[i * 64 + f];
        t.x = fmaxf(t.x, 0.f); t.y = fmaxf(t.y, 0.f);
        t.z = fmaxf(t.z, 0.f); t.w = fmaxf(t.w, 0.f);
        xsv[i * 64 + f] = t;
    }
    __syncthreads();

    float acc[16];
#pragma unroll
    for (int r = 0; r < 16; ++r) acc[r] = b2[f];

#pragma unroll 4
    for (int k = 0; k < HID_F; ++k) {
        float w = w2[k * N_CLS + f];
#pragma unroll
        for (int r = 0; r < 16; ++r) acc[r] += xs[r][k] * w;
    }
#pragma unroll
    for (int r = 0; r < 16; ++r)
        h2[(size_t)(row0 + r) * N_CLS + f] = acc[r];
}

// ---------------- zero-fill (d_ws / d_out are poisoned 0xAA) ----------------
__global__ void zero_kernel(float4* __restrict__ p, int n4)
{
    int i = blockIdx.x * blockDim.x + threadIdx.x;
    if (i < n4) p[i] = make_float4(0.f, 0.f, 0.f, 0.f);
}

// ---------------- SpMM via per-edge scatter atomics ----------------
// F=128: block (128,2) -> 2 edges/block. Wave lanes cover contiguous features,
// so gather loads and atomicAdds are 256B-coalesced; only edge->edge is random.
__global__ __launch_bounds__(256) void spmm128_kernel(
    const int* __restrict__ row, const int* __restrict__ col,
    const float* __restrict__ val, const float* __restrict__ src,
    float* __restrict__ dst)
{
    const int e = blockIdx.x * 2 + threadIdx.y;
    const int f = threadIdx.x;
    const int r = row[e];
    const int c = col[e];
    const float v = val[e];
    atomicAdd(&dst[(size_t)r * HID_F + f], v * src[(size_t)c * HID_F + f]);
}

// F=64: block (64,4) -> 4 edges/block.
__global__ __launch_bounds__(256) void spmm64_kernel(
    const int* __restrict__ row, const int* __restrict__ col,
    const float* __restrict__ val, const float* __restrict__ src,
    float* __restrict__ dst)
{
    const int e = blockIdx.x * 4 + threadIdx.y;
    const int f = threadIdx.x;
    const int r = row[e];
    const int c = col[e];
    const float v = val[e];
    atomicAdd(&dst[(size_t)r * N_CLS + f], v * src[(size_t)c * N_CLS + f]);
}

extern "C" void kernel_launch(void* const* d_in, const int* in_sizes, int n_in,
                              void* d_out, int out_size, void* d_ws, size_t ws_size,
                              hipStream_t stream)
{
    const float* x       = (const float*)d_in[0];
    const int*   adj_row = (const int*)  d_in[1];
    const int*   adj_col = (const int*)  d_in[2];
    const float* adj_val = (const float*)d_in[3];
    const float* w1      = (const float*)d_in[4];
    const float* b1      = (const float*)d_in[5];
    const float* w2      = (const float*)d_in[6];
    const float* b2      = (const float*)d_in[7];
    float*       out     = (float*)d_out;

    // workspace: [h0: N*128] [h1: N*128]; h2 reuses h0's slot (dead after spmm1)
    float* h0 = (float*)d_ws;
    float* h1 = h0 + (size_t)N_NODES * HID_F;
    float* h2 = h0;

    // conv1 projection
    gemm1_kernel<<<N_NODES / 8, 128, 0, stream>>>(x, w1, b1, h0);

    // conv1 aggregation
    const int n4_h1 = N_NODES * HID_F / 4;
    zero_kernel<<<(n4_h1 + 255) / 256, 256, 0, stream>>>((float4*)h1, n4_h1);
    spmm128_kernel<<<N_EDGES / 2, dim3(128, 2), 0, stream>>>(
        adj_row, adj_col, adj_val, h0, h1);

    // conv2 projection (relu fused)
    gemm2_kernel<<<N_NODES / 16, 64, 0, stream>>>(h1, w2, b2, h2);

    // conv2 aggregation
    const int n4_out = N_NODES * N_CLS / 4;
    zero_kernel<<<(n4_out + 255) / 256, 256, 0, stream>>>((float4*)out, n4_out);
    spmm64_kernel<<<N_EDGES / 4, dim3(64, 4), 0, stream>>>(
        adj_row, adj_col, adj_val, h2, out);
}

// Round 2
// 1159.553 us; speedup vs baseline: 1.3909x; 1.3909x over previous
//
#include <hip/hip_runtime.h>

// GCN forward on MI355X — round 2: CSR-gather SpMM (no scatter atomics).
//
// Pipeline (CSR built once per call, used by both SpMMs):
//   zero cursor -> histogram(row) -> 1-block scan -> scatter (col_s, val_s)
//   h0b = bf16(x@w1 + b1)              [100000 x 128]  (bf16 halves gather BW)
//   h1  = spmm_gather(CSR, h0b)        [100000 x 128]  fp32
//   h2  = relu(h1)@w2 + b2             [100000 x 64]   fp32 (reuses h0b slot)
//   out = spmm_gather(CSR, h2)         [100000 x 64]
//
// Workspace map (bytes):
//   h0b/h2 : 25.6 MB   h1 : 51.2 MB   col_s : 6.4 MB   val_s : 6.4 MB
//   row_ptr: 400 KB    cursor: 400 KB                  peak ~90.4 MB

#include <hip/hip_bf16.h>

constexpr int N_NODES = 100000;
constexpr int IN_F    = 512;
constexpr int HID_F   = 128;
constexpr int N_CLS   = 64;
constexpr int N_EDGES = 1600000;

static __device__ __forceinline__ unsigned short f2bf(float x) {
    unsigned int u = __float_as_uint(x);
    unsigned int r = (u + 0x7FFFu + ((u >> 16) & 1u)) >> 16;   // RNE
    return (unsigned short)r;
}
static __device__ __forceinline__ float bf2f(unsigned short u) {
    return __uint_as_float(((unsigned int)u) << 16);
}

// ---------------- CSR build ----------------
__global__ void zero_int_kernel(int* __restrict__ p, int n)
{
    int i = blockIdx.x * blockDim.x + threadIdx.x;
    if (i < n) p[i] = 0;
}

__global__ void hist_kernel(const int* __restrict__ row, int* __restrict__ counts)
{
    int e = blockIdx.x * blockDim.x + threadIdx.x;
    if (e < N_EDGES) atomicAdd(&counts[row[e]], 1);
}

// single-block exclusive scan of counts[0..N) -> row_ptr[0..N]; also primes cursor.
__global__ __launch_bounds__(1024) void scan_kernel(
    const int* __restrict__ counts, int* __restrict__ row_ptr,
    int* __restrict__ cursor)
{
    __shared__ int sdata[1024];
    const int t = threadIdx.x;
    const int chunk = (N_NODES + 1023) / 1024;     // 98
    const int lo = t * chunk;
    const int hi = min(N_NODES, lo + chunk);

    int local = 0;
    for (int i = lo; i < hi; ++i) local += counts[i];
    sdata[t] = local;
    __syncthreads();
    for (int off = 1; off < 1024; off <<= 1) {
        int v = (t >= off) ? sdata[t - off] : 0;
        __syncthreads();
        sdata[t] += v;
        __syncthreads();
    }
    int running = sdata[t] - local;                 // exclusive offset
    for (int i = lo; i < hi; ++i) {
        int c = counts[i];
        row_ptr[i] = running;
        cursor[i]  = running;
        running += c;
    }
    if (t == 1023) row_ptr[N_NODES] = N_EDGES;
}

__global__ void scatter_kernel(
    const int* __restrict__ row, const int* __restrict__ col,
    const float* __restrict__ val, int* __restrict__ cursor,
    int* __restrict__ col_s, float* __restrict__ val_s)
{
    int e = blockIdx.x * blockDim.x + threadIdx.x;
    if (e < N_EDGES) {
        int pos = atomicAdd(&cursor[row[e]], 1);
        col_s[pos] = col[e];
        val_s[pos] = val[e];
    }
}

// ---------------- GEMM1: h0b = bf16(x @ w1 + b1) ----------------
__global__ __launch_bounds__(128) void gemm1_kernel(
    const float* __restrict__ x, const float* __restrict__ w1,
    const float* __restrict__ b1, unsigned short* __restrict__ h0b)
{
    __shared__ float xs[8][IN_F];
    const int f = threadIdx.x;          // 0..127
    const int row0 = blockIdx.x * 8;

    const float4* xv  = (const float4*)(x + (size_t)row0 * IN_F);
    float4*       xsv = (float4*)(&xs[0][0]);
#pragma unroll
    for (int i = 0; i < 8; ++i)
        xsv[i * 128 + f] = xv[i * 128 + f];
    __syncthreads();

    float acc[8];
#pragma unroll
    for (int r = 0; r < 8; ++r) acc[r] = b1[f];

#pragma unroll 4
    for (int k = 0; k < IN_F; ++k) {
        float w = w1[k * HID_F + f];
#pragma unroll
        for (int r = 0; r < 8; ++r) acc[r] += xs[r][k] * w;
    }
#pragma unroll
    for (int r = 0; r < 8; ++r)
        h0b[(size_t)(row0 + r) * HID_F + f] = f2bf(acc[r]);
}

// ---------------- SpMM1 gather: h1[r] = sum_j val*h0b[col] (F=128) ----------
// wave-per-row; lane handles 2 features as bf16x2 (4 B/lane, 256 B/wave/edge).
__global__ __launch_bounds__(256) void spmm_g128_kernel(
    const int* __restrict__ rp, const int* __restrict__ cs,
    const float* __restrict__ vs, const unsigned short* __restrict__ src,
    float* __restrict__ dst)
{
    const int r = blockIdx.x * 4 + threadIdx.y;
    if (r >= N_NODES) return;
    const int lane = threadIdx.x;       // 0..63
    const int j0 = rp[r], j1 = rp[r + 1];

    float ax = 0.f, ay = 0.f;
    int j = j0;
    for (; j + 1 < j1; j += 2) {        // 2-edge unroll: 2 gathers in flight
        int   c0 = cs[j],     c1 = cs[j + 1];
        float v0 = vs[j],     v1 = vs[j + 1];
        ushort2 u0 = ((const ushort2*)(src + (size_t)c0 * HID_F))[lane];
        ushort2 u1 = ((const ushort2*)(src + (size_t)c1 * HID_F))[lane];
        ax += v0 * bf2f(u0.x) + v1 * bf2f(u1.x);
        ay += v0 * bf2f(u0.y) + v1 * bf2f(u1.y);
    }
    if (j < j1) {
        int c = cs[j]; float v = vs[j];
        ushort2 u = ((const ushort2*)(src + (size_t)c * HID_F))[lane];
        ax += v * bf2f(u.x);
        ay += v * bf2f(u.y);
    }
    ((float2*)(dst + (size_t)r * HID_F))[lane] = make_float2(ax, ay);
}

// ---------------- GEMM2: h2 = relu(h1) @ w2 + b2 ----------------
__global__ __launch_bounds__(64) void gemm2_kernel(
    const float* __restrict__ h1, const float* __restrict__ w2,
    const float* __restrict__ b2, float* __restrict__ h2)
{
    __shared__ float xs[16][HID_F];
    const int f = threadIdx.x;          // 0..63
    const int row0 = blockIdx.x * 16;

    const float4* xv  = (const float4*)(h1 + (size_t)row0 * HID_F);
    float4*       xsv = (float4*)(&xs[0][0]);
#pragma unroll
    for (int i = 0; i < 8; ++i) {
        float4 t = xv[i * 64 + f];
        t.x = fmaxf(t.x, 0.f); t.y = fmaxf(t.y, 0.f);
        t.z = fmaxf(t.z, 0.f); t.w = fmaxf(t.w, 0.f);
        xsv[i * 64 + f] = t;
    }
    __syncthreads();

    float acc[16];
#pragma unroll
    for (int r = 0; r < 16; ++r) acc[r] = b2[f];

#pragma unroll 4
    for (int k = 0; k < HID_F; ++k) {
        float w = w2[k * N_CLS + f];
#pragma unroll
        for (int r = 0; r < 16; ++r) acc[r] += xs[r][k] * w;
    }
#pragma unroll
    for (int r = 0; r < 16; ++r)
        h2[(size_t)(row0 + r) * N_CLS + f] = acc[r];
}

// ---------------- SpMM2 gather (F=64): out[r] = sum_j val*h2[col] ----------
__global__ __launch_bounds__(256) void spmm_g64_kernel(
    const int* __restrict__ rp, const int* __restrict__ cs,
    const float* __restrict__ vs, const float* __restrict__ src,
    float* __restrict__ dst)
{
    const int r = blockIdx.x * 4 + threadIdx.y;
    if (r >= N_NODES) return;
    const int lane = threadIdx.x;       // 0..63
    const int j0 = rp[r], j1 = rp[r + 1];

    float acc = 0.f;
    int j = j0;
    for (; j + 1 < j1; j += 2) {
        int   c0 = cs[j],     c1 = cs[j + 1];
        float v0 = vs[j],     v1 = vs[j + 1];
        float a0 = src[(size_t)c0 * N_CLS + lane];
        float a1 = src[(size_t)c1 * N_CLS + lane];
        acc += v0 * a0 + v1 * a1;
    }
    if (j < j1) {
        acc += vs[j] * src[(size_t)cs[j] * N_CLS + lane];
    }
    dst[(size_t)r * N_CLS + lane] = acc;
}

extern "C" void kernel_launch(void* const* d_in, const int* in_sizes, int n_in,
                              void* d_out, int out_size, void* d_ws, size_t ws_size,
                              hipStream_t stream)
{
    const float* x       = (const float*)d_in[0];
    const int*   adj_row = (const int*)  d_in[1];
    const int*   adj_col = (const int*)  d_in[2];
    const float* adj_val = (const float*)d_in[3];
    const float* w1      = (const float*)d_in[4];
    const float* b1      = (const float*)d_in[5];
    const float* w2      = (const float*)d_in[6];
    const float* b2      = (const float*)d_in[7];
    float*       out     = (float*)d_out;

    // workspace carve-up
    char* ws = (char*)d_ws;
    unsigned short* h0b   = (unsigned short*)ws;                 // 25.6 MB
    float*          h2    = (float*)ws;                          // reuses h0b slot
    float*          h1    = (float*)(ws + (size_t)25600000);     // 51.2 MB
    int*            col_s = (int*)  (ws + (size_t)76800000);     // 6.4 MB
    float*          val_s = (float*)(ws + (size_t)83200000);     // 6.4 MB
    int*            rp    = (int*)  (ws + (size_t)89600000);     // 400 KB
    int*            cur   = (int*)  (ws + (size_t)90000004);     // 400 KB

    // ---- CSR build (once; both spmms reuse) ----
    zero_int_kernel<<<(N_NODES + 255) / 256, 256, 0, stream>>>(cur, N_NODES);
    hist_kernel<<<(N_EDGES + 255) / 256, 256, 0, stream>>>(adj_row, cur);
    scan_kernel<<<1, 1024, 0, stream>>>(cur, rp, cur);
    scatter_kernel<<<(N_EDGES + 255) / 256, 256, 0, stream>>>(
        adj_row, adj_col, adj_val, cur, col_s, val_s);

    // ---- conv1 ----
    gemm1_kernel<<<N_NODES / 8, 128, 0, stream>>>(x, w1, b1, h0b);
    spmm_g128_kernel<<<(N_NODES + 3) / 4, dim3(64, 4), 0, stream>>>(
        rp, col_s, val_s, h0b, h1);

    // ---- conv2 ----
    gemm2_kernel<<<N_NODES / 16, 64, 0, stream>>>(h1, w2, b2, h2);
    spmm_g64_kernel<<<(N_NODES + 3) / 4, dim3(64, 4), 0, stream>>>(
        rp, col_s, val_s, h2, out);
}

// Round 3
// 970.320 us; speedup vs baseline: 1.6621x; 1.1950x over previous
//
#include <hip/hip_runtime.h>
#include <hip/hip_bf16.h>

// GCN forward on MI355X — round 3: MFMA gemm1 + bf16 intermediates.
//
//   w1t = bf16(w1^T)  [128 n][512 k]      (tiny transpose kernel, L2-resident)
//   CSR build: zero -> hist -> scan -> scatter
//   h0b = bf16(x@w1 + b1)    via MFMA     [100000 x 128] bf16
//   h1r = bf16(relu(spmm(A, h0b)))        [100000 x 128] bf16
//   h2  = h1r@w2 + b2                     [100000 x 64]  fp32 (precision guard)
//   out = spmm(A, h2)                     [100000 x 64]  fp32

constexpr int N_NODES = 100000;
constexpr int IN_F    = 512;
constexpr int HID_F   = 128;
constexpr int N_CLS   = 64;
constexpr int N_EDGES = 1600000;

typedef __attribute__((ext_vector_type(8))) short short8;
typedef __attribute__((ext_vector_type(4))) float f32x4;

static __device__ __forceinline__ unsigned short f2bf(float x) {
    unsigned int u = __float_as_uint(x);
    unsigned int r = (u + 0x7FFFu + ((u >> 16) & 1u)) >> 16;   // RNE
    return (unsigned short)r;
}
static __device__ __forceinline__ float bf2f(unsigned short u) {
    return __uint_as_float(((unsigned int)u) << 16);
}

// ---------------- w1 transpose + bf16: w1t[n][k] = bf16(w1[k][n]) ------------
__global__ void w1t_kernel(const float* __restrict__ w1, unsigned short* __restrict__ w1t)
{
    int idx = blockIdx.x * 256 + threadIdx.x;      // 65536 = 128*512, n-major
    int n = idx >> 9, k = idx & 511;
    w1t[idx] = f2bf(w1[k * HID_F + n]);            // writes coalesced
}

// ---------------- CSR build ----------------
__global__ void zero_int_kernel(int* __restrict__ p, int n)
{
    int i = blockIdx.x * blockDim.x + threadIdx.x;
    if (i < n) p[i] = 0;
}

__global__ void hist_kernel(const int* __restrict__ row, int* __restrict__ counts)
{
    int e = blockIdx.x * blockDim.x + threadIdx.x;
    if (e < N_EDGES) atomicAdd(&counts[row[e]], 1);
}

__global__ __launch_bounds__(1024) void scan_kernel(
    const int* __restrict__ counts, int* __restrict__ row_ptr,
    int* __restrict__ cursor)
{
    __shared__ int sdata[1024];
    const int t = threadIdx.x;
    const int chunk = (N_NODES + 1023) / 1024;
    const int lo = t * chunk;
    const int hi = min(N_NODES, lo + chunk);

    int local = 0;
    for (int i = lo; i < hi; ++i) local += counts[i];
    sdata[t] = local;
    __syncthreads();
    for (int off = 1; off < 1024; off <<= 1) {
        int v = (t >= off) ? sdata[t - off] : 0;
        __syncthreads();
        sdata[t] += v;
        __syncthreads();
    }
    int running = sdata[t] - local;
    for (int i = lo; i < hi; ++i) {
        int c = counts[i];
        row_ptr[i] = running;
        cursor[i]  = running;
        running += c;
    }
    if (t == 1023) row_ptr[N_NODES] = N_EDGES;
}

__global__ void scatter_kernel(
    const int* __restrict__ row, const int* __restrict__ col,
    const float* __restrict__ val, int* __restrict__ cursor,
    int* __restrict__ col_s, float* __restrict__ val_s)
{
    int e = blockIdx.x * blockDim.x + threadIdx.x;
    if (e < N_EDGES) {
        int pos = atomicAdd(&cursor[row[e]], 1);
        col_s[pos] = col[e];
        val_s[pos] = val[e];
    }
}

// ---------------- GEMM1 via MFMA: h0b = bf16(x @ w1 + b1) -------------------
// One wave per 32 rows x all 128 cols. 100000 = 3125 * 32 exactly (no tail).
// A-frags: x fp32 loaded 8 floats/lane, converted to bf16 in-register.
// B-frags: w1t[n][k] bf16, k-contiguous 16B loads (L2-resident, 128 KB).
// Frag layouts (m89/m120 verified): A[m=lane&15][k=quad*8+j], B[n=lane&15][k=quad*8+j],
// C/D: col=lane&15, row=quad*4+reg.
__global__ __launch_bounds__(64) void gemm1_mfma_kernel(
    const float* __restrict__ x, const unsigned short* __restrict__ w1t,
    const float* __restrict__ b1, unsigned short* __restrict__ h0b)
{
    const int lane = threadIdx.x;
    const int row0 = blockIdx.x * 32;
    const int m = lane & 15;
    const int q = lane >> 4;

    f32x4 acc[2][8];
#pragma unroll
    for (int mi = 0; mi < 2; ++mi)
#pragma unroll
        for (int ni = 0; ni < 8; ++ni)
            acc[mi][ni] = (f32x4){0.f, 0.f, 0.f, 0.f};

    union U8 { short8 v; __hip_bfloat162 h[4]; };

    const float* a0p = x + (size_t)(row0 + m)      * IN_F + q * 8;
    const float* a1p = x + (size_t)(row0 + 16 + m) * IN_F + q * 8;
    const unsigned short* bp = w1t + (size_t)m * IN_F + q * 8;

    for (int kk = 0; kk < IN_F; kk += 32) {
        // A fragments: 8 fp32 per lane per m-tile -> bf16x8
        short8 a[2];
#pragma unroll
        for (int mi = 0; mi < 2; ++mi) {
            const float4* p = (const float4*)((mi ? a1p : a0p) + kk);
            float4 lo = p[0], hi = p[1];
            U8 u;
            u.h[0] = __float22bfloat162_rn(make_float2(lo.x, lo.y));
            u.h[1] = __float22bfloat162_rn(make_float2(lo.z, lo.w));
            u.h[2] = __float22bfloat162_rn(make_float2(hi.x, hi.y));
            u.h[3] = __float22bfloat162_rn(make_float2(hi.z, hi.w));
            a[mi] = u.v;
        }
        // B fragments + MFMA
#pragma unroll
        for (int ni = 0; ni < 8; ++ni) {
            short8 b = *(const short8*)(bp + (size_t)ni * 16 * IN_F + kk);
            acc[0][ni] = __builtin_amdgcn_mfma_f32_16x16x32_bf16(a[0], b, acc[0][ni], 0, 0, 0);
            acc[1][ni] = __builtin_amdgcn_mfma_f32_16x16x32_bf16(a[1], b, acc[1][ni], 0, 0, 0);
        }
    }

    // epilogue: + bias, -> bf16, store
    float bias[8];
#pragma unroll
    for (int ni = 0; ni < 8; ++ni) bias[ni] = b1[ni * 16 + m];

#pragma unroll
    for (int mi = 0; mi < 2; ++mi)
#pragma unroll
        for (int r = 0; r < 4; ++r) {
            int row = row0 + mi * 16 + q * 4 + r;
            unsigned short* dst = h0b + (size_t)row * HID_F;
#pragma unroll
            for (int ni = 0; ni < 8; ++ni)
                dst[ni * 16 + m] = f2bf(acc[mi][ni][r] + bias[ni]);
        }
}

// ---------------- SpMM1 gather: h1r = bf16(relu(sum val*h0b[col])) ----------
__global__ __launch_bounds__(256) void spmm_g128_kernel(
    const int* __restrict__ rp, const int* __restrict__ cs,
    const float* __restrict__ vs, const unsigned short* __restrict__ src,
    unsigned short* __restrict__ dst)
{
    const int r = blockIdx.x * 4 + threadIdx.y;
    if (r >= N_NODES) return;
    const int lane = threadIdx.x;
    const int j0 = rp[r], j1 = rp[r + 1];

    float ax = 0.f, ay = 0.f;
    int j = j0;
    for (; j + 1 < j1; j += 2) {
        int   c0 = cs[j],     c1 = cs[j + 1];
        float v0 = vs[j],     v1 = vs[j + 1];
        ushort2 u0 = ((const ushort2*)(src + (size_t)c0 * HID_F))[lane];
        ushort2 u1 = ((const ushort2*)(src + (size_t)c1 * HID_F))[lane];
        ax += v0 * bf2f(u0.x) + v1 * bf2f(u1.x);
        ay += v0 * bf2f(u0.y) + v1 * bf2f(u1.y);
    }
    if (j < j1) {
        int c = cs[j]; float v = vs[j];
        ushort2 u = ((const ushort2*)(src + (size_t)c * HID_F))[lane];
        ax += v * bf2f(u.x);
        ay += v * bf2f(u.y);
    }
    ushort2 o;
    o.x = f2bf(fmaxf(ax, 0.f));     // relu fused here
    o.y = f2bf(fmaxf(ay, 0.f));
    ((ushort2*)(dst + (size_t)r * HID_F))[lane] = o;
}

// ---------------- GEMM2: h2 = h1r @ w2 + b2 (relu pre-applied) --------------
__global__ __launch_bounds__(64) void gemm2_kernel(
    const unsigned short* __restrict__ h1r, const float* __restrict__ w2,
    const float* __restrict__ b2, float* __restrict__ h2)
{
    __shared__ float xs[16][HID_F];
    const int f = threadIdx.x;          // 0..63
    const int row0 = blockIdx.x * 16;

    const ushort2* xv = (const ushort2*)(h1r + (size_t)row0 * HID_F);
    float2* xsv = (float2*)(&xs[0][0]);
#pragma unroll
    for (int i = 0; i < 16; ++i) {
        ushort2 u = xv[i * 64 + f];
        xsv[i * 64 + f] = make_float2(bf2f(u.x), bf2f(u.y));
    }
    __syncthreads();

    float acc[16];
#pragma unroll
    for (int r = 0; r < 16; ++r) acc[r] = b2[f];

#pragma unroll 4
    for (int k = 0; k < HID_F; ++k) {
        float w = w2[k * N_CLS + f];
#pragma unroll
        for (int r = 0; r < 16; ++r) acc[r] += xs[r][k] * w;
    }
#pragma unroll
    for (int r = 0; r < 16; ++r)
        h2[(size_t)(row0 + r) * N_CLS + f] = acc[r];
}

// ---------------- SpMM2 gather (F=64): out = sum val*h2[col] ----------------
__global__ __launch_bounds__(256) void spmm_g64_kernel(
    const int* __restrict__ rp, const int* __restrict__ cs,
    const float* __restrict__ vs, const float* __restrict__ src,
    float* __restrict__ dst)
{
    const int r = blockIdx.x * 4 + threadIdx.y;
    if (r >= N_NODES) return;
    const int lane = threadIdx.x;
    const int j0 = rp[r], j1 = rp[r + 1];

    float acc = 0.f;
    int j = j0;
    for (; j + 1 < j1; j += 2) {
        int   c0 = cs[j],     c1 = cs[j + 1];
        float v0 = vs[j],     v1 = vs[j + 1];
        acc += v0 * src[(size_t)c0 * N_CLS + lane] + v1 * src[(size_t)c1 * N_CLS + lane];
    }
    if (j < j1) acc += vs[j] * src[(size_t)cs[j] * N_CLS + lane];
    dst[(size_t)r * N_CLS + lane] = acc;
}

extern "C" void kernel_launch(void* const* d_in, const int* in_sizes, int n_in,
                              void* d_out, int out_size, void* d_ws, size_t ws_size,
                              hipStream_t stream)
{
    const float* x       = (const float*)d_in[0];
    const int*   adj_row = (const int*)  d_in[1];
    const int*   adj_col = (const int*)  d_in[2];
    const float* adj_val = (const float*)d_in[3];
    const float* w1      = (const float*)d_in[4];
    const float* b1      = (const float*)d_in[5];
    const float* w2      = (const float*)d_in[6];
    const float* b2      = (const float*)d_in[7];
    float*       out     = (float*)d_out;

    // workspace carve-up (all offsets 16B-aligned)
    char* ws = (char*)d_ws;
    unsigned short* h0b   = (unsigned short*)ws;                  // 25.6 MB
    unsigned short* h1r   = (unsigned short*)(ws + 25600000);     // 25.6 MB
    float*          h2    = (float*)(ws + 51200000);              // 25.6 MB
    int*            col_s = (int*)  (ws + 76800000);              // 6.4 MB
    float*          val_s = (float*)(ws + 83200000);              // 6.4 MB
    int*            rp    = (int*)  (ws + 89600000);              // 400 KB + 4
    int*            cur   = (int*)  (ws + 90000016);              // 400 KB
    unsigned short* w1t   = (unsigned short*)(ws + 90400016);     // 128 KB

    // ---- prep ----
    w1t_kernel<<<IN_F * HID_F / 256, 256, 0, stream>>>(w1, w1t);
    zero_int_kernel<<<(N_NODES + 255) / 256, 256, 0, stream>>>(cur, N_NODES);
    hist_kernel<<<(N_EDGES + 255) / 256, 256, 0, stream>>>(adj_row, cur);
    scan_kernel<<<1, 1024, 0, stream>>>(cur, rp, cur);
    scatter_kernel<<<(N_EDGES + 255) / 256, 256, 0, stream>>>(
        adj_row, adj_col, adj_val, cur, col_s, val_s);

    // ---- conv1 ----
    gemm1_mfma_kernel<<<N_NODES / 32, 64, 0, stream>>>(x, w1t, b1, h0b);
    spmm_g128_kernel<<<(N_NODES + 3) / 4, dim3(64, 4), 0, stream>>>(
        rp, col_s, val_s, h0b, h1r);

    // ---- conv2 ----
    gemm2_kernel<<<N_NODES / 16, 64, 0, stream>>>(h1r, w2, b2, h2);
    spmm_g64_kernel<<<(N_NODES + 3) / 4, dim3(64, 4), 0, stream>>>(
        rp, col_s, val_s, h2, out);
}

// Round 4
// 723.567 us; speedup vs baseline: 2.2289x; 1.3410x over previous
//
#include <hip/hip_runtime.h>
#include <hip/hip_bf16.h>

// GCN forward on MI355X — round 4: hierarchical scan + packed edges.
//
//   w1t = bf16(w1^T)  [128 n][512 k]
//   CSR build: zero -> hist -> scanA/B/C (hierarchical) -> scatter (int2 edges)
//   h0b = bf16(x@w1 + b1)    via MFMA     [100000 x 128] bf16
//   h1r = bf16(relu(spmm(A, h0b)))        [100000 x 128] bf16
//   h2  = h1r@w2 + b2                     [100000 x 64]  fp32
//   out = spmm(A, h2)                     [100000 x 64]  fp32

constexpr int N_NODES = 100000;
constexpr int IN_F    = 512;
constexpr int HID_F   = 128;
constexpr int N_CLS   = 64;
constexpr int N_EDGES = 1600000;

constexpr int SCAN_BLOCK    = 256;
constexpr int N_SCAN_BLOCKS = (N_NODES + SCAN_BLOCK - 1) / SCAN_BLOCK;  // 391

typedef __attribute__((ext_vector_type(8))) short short8;
typedef __attribute__((ext_vector_type(4))) float f32x4;

static __device__ __forceinline__ unsigned short f2bf(float x) {
    unsigned int u = __float_as_uint(x);
    unsigned int r = (u + 0x7FFFu + ((u >> 16) & 1u)) >> 16;   // RNE
    return (unsigned short)r;
}
static __device__ __forceinline__ float bf2f(unsigned short u) {
    return __uint_as_float(((unsigned int)u) << 16);
}

// ---------------- w1 transpose + bf16 ----------------
__global__ void w1t_kernel(const float* __restrict__ w1, unsigned short* __restrict__ w1t)
{
    int idx = blockIdx.x * 256 + threadIdx.x;      // 65536 = 128*512, n-major
    int n = idx >> 9, k = idx & 511;
    w1t[idx] = f2bf(w1[k * HID_F + n]);
}

// ---------------- CSR build ----------------
__global__ void zero_int_kernel(int* __restrict__ p, int n)
{
    int i = blockIdx.x * blockDim.x + threadIdx.x;
    if (i < n) p[i] = 0;
}

__global__ void hist_kernel(const int* __restrict__ row, int* __restrict__ counts)
{
    int e = blockIdx.x * blockDim.x + threadIdx.x;
    if (e < N_EDGES) atomicAdd(&counts[row[e]], 1);
}

// Phase A: block-local exclusive scan (256 wide) + per-block total
__global__ __launch_bounds__(SCAN_BLOCK) void scanA_kernel(
    const int* __restrict__ counts, int* __restrict__ local_ex,
    int* __restrict__ blockSums)
{
    __shared__ int s[SCAN_BLOCK];
    const int t = threadIdx.x;
    const int i = blockIdx.x * SCAN_BLOCK + t;
    int v = (i < N_NODES) ? counts[i] : 0;
    s[t] = v;
    __syncthreads();
    for (int off = 1; off < SCAN_BLOCK; off <<= 1) {
        int u = (t >= off) ? s[t - off] : 0;
        __syncthreads();
        s[t] += u;
        __syncthreads();
    }
    if (i < N_NODES) local_ex[i] = s[t] - v;
    if (t == SCAN_BLOCK - 1) blockSums[blockIdx.x] = s[t];
}

// Phase B: single 512-thread block, exclusive scan of 391 block sums in-place
__global__ __launch_bounds__(512) void scanB_kernel(int* __restrict__ blockSums)
{
    __shared__ int s[512];
    const int t = threadIdx.x;
    int v = (t < N_SCAN_BLOCKS) ? blockSums[t] : 0;
    s[t] = v;
    __syncthreads();
    for (int off = 1; off < 512; off <<= 1) {
        int u = (t >= off) ? s[t - off] : 0;
        __syncthreads();
        s[t] += u;
        __syncthreads();
    }
    if (t < N_SCAN_BLOCKS) blockSums[t] = s[t] - v;   // exclusive
}

// Phase C: final row_ptr / cursor
__global__ __launch_bounds__(SCAN_BLOCK) void scanC_kernel(
    const int* __restrict__ local_ex, const int* __restrict__ blockSums,
    int* __restrict__ row_ptr, int* __restrict__ cursor)
{
    const int i = blockIdx.x * SCAN_BLOCK + threadIdx.x;
    if (i < N_NODES) {
        int v = local_ex[i] + blockSums[blockIdx.x];
        row_ptr[i] = v;
        cursor[i]  = v;
    }
    if (i == 0) row_ptr[N_NODES] = N_EDGES;
}

// scatter: pack (col, val) into one int2 per edge
__global__ void scatter_kernel(
    const int* __restrict__ row, const int* __restrict__ col,
    const float* __restrict__ val, int* __restrict__ cursor,
    int2* __restrict__ es)
{
    int e = blockIdx.x * blockDim.x + threadIdx.x;
    if (e < N_EDGES) {
        int pos = atomicAdd(&cursor[row[e]], 1);
        es[pos] = make_int2(col[e], __float_as_int(val[e]));
    }
}

// ---------------- GEMM1 via MFMA: h0b = bf16(x @ w1 + b1) -------------------
__global__ __launch_bounds__(64) void gemm1_mfma_kernel(
    const float* __restrict__ x, const unsigned short* __restrict__ w1t,
    const float* __restrict__ b1, unsigned short* __restrict__ h0b)
{
    const int lane = threadIdx.x;
    const int row0 = blockIdx.x * 32;
    const int m = lane & 15;
    const int q = lane >> 4;

    f32x4 acc[2][8];
#pragma unroll
    for (int mi = 0; mi < 2; ++mi)
#pragma unroll
        for (int ni = 0; ni < 8; ++ni)
            acc[mi][ni] = (f32x4){0.f, 0.f, 0.f, 0.f};

    union U8 { short8 v; __hip_bfloat162 h[4]; };

    const float* a0p = x + (size_t)(row0 + m)      * IN_F + q * 8;
    const float* a1p = x + (size_t)(row0 + 16 + m) * IN_F + q * 8;
    const unsigned short* bp = w1t + (size_t)m * IN_F + q * 8;

    for (int kk = 0; kk < IN_F; kk += 32) {
        short8 a[2];
#pragma unroll
        for (int mi = 0; mi < 2; ++mi) {
            const float4* p = (const float4*)((mi ? a1p : a0p) + kk);
            float4 lo = p[0], hi = p[1];
            U8 u;
            u.h[0] = __float22bfloat162_rn(make_float2(lo.x, lo.y));
            u.h[1] = __float22bfloat162_rn(make_float2(lo.z, lo.w));
            u.h[2] = __float22bfloat162_rn(make_float2(hi.x, hi.y));
            u.h[3] = __float22bfloat162_rn(make_float2(hi.z, hi.w));
            a[mi] = u.v;
        }
#pragma unroll
        for (int ni = 0; ni < 8; ++ni) {
            short8 b = *(const short8*)(bp + (size_t)ni * 16 * IN_F + kk);
            acc[0][ni] = __builtin_amdgcn_mfma_f32_16x16x32_bf16(a[0], b, acc[0][ni], 0, 0, 0);
            acc[1][ni] = __builtin_amdgcn_mfma_f32_16x16x32_bf16(a[1], b, acc[1][ni], 0, 0, 0);
        }
    }

    float bias[8];
#pragma unroll
    for (int ni = 0; ni < 8; ++ni) bias[ni] = b1[ni * 16 + m];

#pragma unroll
    for (int mi = 0; mi < 2; ++mi)
#pragma unroll
        for (int r = 0; r < 4; ++r) {
            int row = row0 + mi * 16 + q * 4 + r;
            unsigned short* dst = h0b + (size_t)row * HID_F;
#pragma unroll
            for (int ni = 0; ni < 8; ++ni)
                dst[ni * 16 + m] = f2bf(acc[mi][ni][r] + bias[ni]);
        }
}

// ---------------- SpMM1 gather: h1r = bf16(relu(sum val*h0b[col])) ----------
__global__ __launch_bounds__(256) void spmm_g128_kernel(
    const int* __restrict__ rp, const int2* __restrict__ es,
    const unsigned short* __restrict__ src, unsigned short* __restrict__ dst)
{
    const int r = blockIdx.x * 4 + threadIdx.y;
    if (r >= N_NODES) return;
    const int lane = threadIdx.x;
    const int j0 = rp[r], j1 = rp[r + 1];

    float ax = 0.f, ay = 0.f;
    int j = j0;
    for (; j + 3 < j1; j += 4) {        // 4 gathers in flight
        int2 e0 = es[j], e1 = es[j + 1], e2 = es[j + 2], e3 = es[j + 3];
        ushort2 u0 = ((const ushort2*)(src + (size_t)e0.x * HID_F))[lane];
        ushort2 u1 = ((const ushort2*)(src + (size_t)e1.x * HID_F))[lane];
        ushort2 u2 = ((const ushort2*)(src + (size_t)e2.x * HID_F))[lane];
        ushort2 u3 = ((const ushort2*)(src + (size_t)e3.x * HID_F))[lane];
        float v0 = __int_as_float(e0.y), v1 = __int_as_float(e1.y);
        float v2 = __int_as_float(e2.y), v3 = __int_as_float(e3.y);
        ax += v0 * bf2f(u0.x) + v1 * bf2f(u1.x) + v2 * bf2f(u2.x) + v3 * bf2f(u3.x);
        ay += v0 * bf2f(u0.y) + v1 * bf2f(u1.y) + v2 * bf2f(u2.y) + v3 * bf2f(u3.y);
    }
    for (; j < j1; ++j) {
        int2 e = es[j];
        float v = __int_as_float(e.y);
        ushort2 u = ((const ushort2*)(src + (size_t)e.x * HID_F))[lane];
        ax += v * bf2f(u.x);
        ay += v * bf2f(u.y);
    }
    ushort2 o;
    o.x = f2bf(fmaxf(ax, 0.f));
    o.y = f2bf(fmaxf(ay, 0.f));
    ((ushort2*)(dst + (size_t)r * HID_F))[lane] = o;
}

// ---------------- GEMM2: h2 = h1r @ w2 + b2 ----------------
__global__ __launch_bounds__(64) void gemm2_kernel(
    const unsigned short* __restrict__ h1r, const float* __restrict__ w2,
    const float* __restrict__ b2, float* __restrict__ h2)
{
    __shared__ float xs[16][HID_F];
    const int f = threadIdx.x;
    const int row0 = blockIdx.x * 16;

    const ushort2* xv = (const ushort2*)(h1r + (size_t)row0 * HID_F);
    float2* xsv = (float2*)(&xs[0][0]);
#pragma unroll
    for (int i = 0; i < 16; ++i) {
        ushort2 u = xv[i * 64 + f];
        xsv[i * 64 + f] = make_float2(bf2f(u.x), bf2f(u.y));
    }
    __syncthreads();

    float acc[16];
#pragma unroll
    for (int r = 0; r < 16; ++r) acc[r] = b2[f];

#pragma unroll 4
    for (int k = 0; k < HID_F; ++k) {
        float w = w2[k * N_CLS + f];
#pragma unroll
        for (int r = 0; r < 16; ++r) acc[r] += xs[r][k] * w;
    }
#pragma unroll
    for (int r = 0; r < 16; ++r)
        h2[(size_t)(row0 + r) * N_CLS + f] = acc[r];
}

// ---------------- SpMM2 gather (F=64) ----------------
__global__ __launch_bounds__(256) void spmm_g64_kernel(
    const int* __restrict__ rp, const int2* __restrict__ es,
    const float* __restrict__ src, float* __restrict__ dst)
{
    const int r = blockIdx.x * 4 + threadIdx.y;
    if (r >= N_NODES) return;
    const int lane = threadIdx.x;
    const int j0 = rp[r], j1 = rp[r + 1];

    float acc = 0.f;
    int j = j0;
    for (; j + 3 < j1; j += 4) {
        int2 e0 = es[j], e1 = es[j + 1], e2 = es[j + 2], e3 = es[j + 3];
        float a0 = src[(size_t)e0.x * N_CLS + lane];
        float a1 = src[(size_t)e1.x * N_CLS + lane];
        float a2 = src[(size_t)e2.x * N_CLS + lane];
        float a3 = src[(size_t)e3.x * N_CLS + lane];
        acc += __int_as_float(e0.y) * a0 + __int_as_float(e1.y) * a1
             + __int_as_float(e2.y) * a2 + __int_as_float(e3.y) * a3;
    }
    for (; j < j1; ++j) {
        int2 e = es[j];
        acc += __int_as_float(e.y) * src[(size_t)e.x * N_CLS + lane];
    }
    dst[(size_t)r * N_CLS + lane] = acc;
}

extern "C" void kernel_launch(void* const* d_in, const int* in_sizes, int n_in,
                              void* d_out, int out_size, void* d_ws, size_t ws_size,
                              hipStream_t stream)
{
    const float* x       = (const float*)d_in[0];
    const int*   adj_row = (const int*)  d_in[1];
    const int*   adj_col = (const int*)  d_in[2];
    const float* adj_val = (const float*)d_in[3];
    const float* w1      = (const float*)d_in[4];
    const float* b1      = (const float*)d_in[5];
    const float* w2      = (const float*)d_in[6];
    const float* b2      = (const float*)d_in[7];
    float*       out     = (float*)d_out;

    // workspace carve-up
    char* ws = (char*)d_ws;
    unsigned short* h0b   = (unsigned short*)ws;                  // 25.6 MB
    unsigned short* h1r   = (unsigned short*)(ws + 25600000);     // 25.6 MB
    float*          h2    = (float*)(ws + 51200000);              // 25.6 MB
    int2*           es    = (int2*) (ws + 76800000);              // 12.8 MB
    int*            rp    = (int*)  (ws + 89600000);              // 400 KB + 4
    int*            cur   = (int*)  (ws + 90000016);              // 400 KB
    unsigned short* w1t   = (unsigned short*)(ws + 90400016);     // 128 KB
    int*            lex   = (int*)  (ws + 90531088);              // 400 KB
    int*            bsum  = (int*)  (ws + 90931088);              // 1.6 KB

    // ---- prep ----
    w1t_kernel<<<IN_F * HID_F / 256, 256, 0, stream>>>(w1, w1t);
    zero_int_kernel<<<(N_NODES + 255) / 256, 256, 0, stream>>>(cur, N_NODES);
    hist_kernel<<<(N_EDGES + 255) / 256, 256, 0, stream>>>(adj_row, cur);
    scanA_kernel<<<N_SCAN_BLOCKS, SCAN_BLOCK, 0, stream>>>(cur, lex, bsum);
    scanB_kernel<<<1, 512, 0, stream>>>(bsum);
    scanC_kernel<<<N_SCAN_BLOCKS, SCAN_BLOCK, 0, stream>>>(lex, bsum, rp, cur);
    scatter_kernel<<<(N_EDGES + 255) / 256, 256, 0, stream>>>(
        adj_row, adj_col, adj_val, cur, es);

    // ---- conv1 ----
    gemm1_mfma_kernel<<<N_NODES / 32, 64, 0, stream>>>(x, w1t, b1, h0b);
    spmm_g128_kernel<<<(N_NODES + 3) / 4, dim3(64, 4), 0, stream>>>(
        rp, es, h0b, h1r);

    // ---- conv2 ----
    gemm2_kernel<<<N_NODES / 16, 64, 0, stream>>>(h1r, w2, b2, h2);
    spmm_g64_kernel<<<(N_NODES + 3) / 4, dim3(64, 4), 0, stream>>>(
        rp, es, h2, out);
}

// Round 5
// 687.913 us; speedup vs baseline: 2.3445x; 1.0518x over previous
//
#include <hip/hip_runtime.h>
#include <hip/hip_bf16.h>

// GCN forward on MI355X — round 5: latency-tolerant MFMA GEMMs + deeper SpMM MLP.
//
//   w1t = bf16(w1^T) [128][512], w2t = bf16(w2^T) [64][128]
//   CSR build: zero -> hist -> scanA/B/C -> scatter (int2 edges)
//   h0b = bf16(x@w1 + b1)    via MFMA (batched B-frags, A prefetch)
//   h1r = bf16(relu(spmm(A, h0b)))
//   h2  = h1r@w2t + b2       via MFMA (fp32 out)
//   out = spmm(A, h2)

constexpr int N_NODES = 100000;
constexpr int IN_F    = 512;
constexpr int HID_F   = 128;
constexpr int N_CLS   = 64;
constexpr int N_EDGES = 1600000;

constexpr int SCAN_BLOCK    = 256;
constexpr int N_SCAN_BLOCKS = (N_NODES + SCAN_BLOCK - 1) / SCAN_BLOCK;  // 391
constexpr int N_WAVES_G     = N_NODES / 32;                             // 3125

typedef __attribute__((ext_vector_type(8))) short short8;
typedef __attribute__((ext_vector_type(4))) float f32x4;

static __device__ __forceinline__ unsigned short f2bf(float x) {
    unsigned int u = __float_as_uint(x);
    unsigned int r = (u + 0x7FFFu + ((u >> 16) & 1u)) >> 16;   // RNE
    return (unsigned short)r;
}
static __device__ __forceinline__ float bf2f(unsigned short u) {
    return __uint_as_float(((unsigned int)u) << 16);
}

// ---------------- weight transposes -> bf16 ----------------
__global__ void w1t_kernel(const float* __restrict__ w1, unsigned short* __restrict__ w1t)
{
    int idx = blockIdx.x * 256 + threadIdx.x;      // 65536 = 128*512, n-major
    int n = idx >> 9, k = idx & 511;
    w1t[idx] = f2bf(w1[k * HID_F + n]);
}

__global__ void w2t_kernel(const float* __restrict__ w2, unsigned short* __restrict__ w2t)
{
    int idx = blockIdx.x * 256 + threadIdx.x;      // 8192 = 64*128, n-major
    int n = idx >> 7, k = idx & 127;
    w2t[idx] = f2bf(w2[k * N_CLS + n]);
}

// ---------------- CSR build ----------------
__global__ void zero_int_kernel(int* __restrict__ p, int n)
{
    int i = blockIdx.x * blockDim.x + threadIdx.x;
    if (i < n) p[i] = 0;
}

__global__ void hist_kernel(const int* __restrict__ row, int* __restrict__ counts)
{
    int e = blockIdx.x * blockDim.x + threadIdx.x;
    if (e < N_EDGES) atomicAdd(&counts[row[e]], 1);
}

__global__ __launch_bounds__(SCAN_BLOCK) void scanA_kernel(
    const int* __restrict__ counts, int* __restrict__ local_ex,
    int* __restrict__ blockSums)
{
    __shared__ int s[SCAN_BLOCK];
    const int t = threadIdx.x;
    const int i = blockIdx.x * SCAN_BLOCK + t;
    int v = (i < N_NODES) ? counts[i] : 0;
    s[t] = v;
    __syncthreads();
    for (int off = 1; off < SCAN_BLOCK; off <<= 1) {
        int u = (t >= off) ? s[t - off] : 0;
        __syncthreads();
        s[t] += u;
        __syncthreads();
    }
    if (i < N_NODES) local_ex[i] = s[t] - v;
    if (t == SCAN_BLOCK - 1) blockSums[blockIdx.x] = s[t];
}

__global__ __launch_bounds__(512) void scanB_kernel(int* __restrict__ blockSums)
{
    __shared__ int s[512];
    const int t = threadIdx.x;
    int v = (t < N_SCAN_BLOCKS) ? blockSums[t] : 0;
    s[t] = v;
    __syncthreads();
    for (int off = 1; off < 512; off <<= 1) {
        int u = (t >= off) ? s[t - off] : 0;
        __syncthreads();
        s[t] += u;
        __syncthreads();
    }
    if (t < N_SCAN_BLOCKS) blockSums[t] = s[t] - v;
}

__global__ __launch_bounds__(SCAN_BLOCK) void scanC_kernel(
    const int* __restrict__ local_ex, const int* __restrict__ blockSums,
    int* __restrict__ row_ptr, int* __restrict__ cursor)
{
    const int i = blockIdx.x * SCAN_BLOCK + threadIdx.x;
    if (i < N_NODES) {
        int v = local_ex[i] + blockSums[blockIdx.x];
        row_ptr[i] = v;
        cursor[i]  = v;
    }
    if (i == 0) row_ptr[N_NODES] = N_EDGES;
}

__global__ void scatter_kernel(
    const int* __restrict__ row, const int* __restrict__ col,
    const float* __restrict__ val, int* __restrict__ cursor,
    int2* __restrict__ es)
{
    int e = blockIdx.x * blockDim.x + threadIdx.x;
    if (e < N_EDGES) {
        int pos = atomicAdd(&cursor[row[e]], 1);
        es[pos] = make_int2(col[e], __float_as_int(val[e]));
    }
}

// ---------------- GEMM1 via MFMA: h0b = bf16(x @ w1 + b1) -------------------
// 4 independent waves/block; each wave: 32 rows x 128 cols.
// Per K-tile: batch-load all 8 B-frags (one vmcnt drain, not 8 serial
// round-trips), prefetch next A-tile (HBM) before the MFMA section.
__global__ __launch_bounds__(256) void gemm1_mfma_kernel(
    const float* __restrict__ x, const unsigned short* __restrict__ w1t,
    const float* __restrict__ b1, unsigned short* __restrict__ h0b)
{
    const int lane = threadIdx.x & 63;
    const int wid  = blockIdx.x * 4 + (threadIdx.x >> 6);
    if (wid >= N_WAVES_G) return;
    const int row0 = wid * 32;
    const int m = lane & 15;
    const int q = lane >> 4;

    f32x4 acc[2][8];
#pragma unroll
    for (int mi = 0; mi < 2; ++mi)
#pragma unroll
        for (int ni = 0; ni < 8; ++ni)
            acc[mi][ni] = (f32x4){0.f, 0.f, 0.f, 0.f};

    union U8 { short8 v; __hip_bfloat162 h[4]; };

    const float* a0p = x + (size_t)(row0 + m)      * IN_F + q * 8;
    const float* a1p = x + (size_t)(row0 + 16 + m) * IN_F + q * 8;
    const unsigned short* bp = w1t + (size_t)m * IN_F + q * 8;

    // prefetch first A tile
    float4 c0l = ((const float4*)a0p)[0];
    float4 c0h = ((const float4*)a0p)[1];
    float4 c1l = ((const float4*)a1p)[0];
    float4 c1h = ((const float4*)a1p)[1];

    for (int kk = 0; kk < IN_F; kk += 32) {
        // all 8 B-frags issued up-front (independent L2-hit loads)
        short8 bf[8];
#pragma unroll
        for (int ni = 0; ni < 8; ++ni)
            bf[ni] = *(const short8*)(bp + (size_t)ni * 16 * IN_F + kk);

        // prefetch next A tile (in flight across the MFMA section)
        float4 n0l, n0h, n1l, n1h;
        if (kk + 32 < IN_F) {
            n0l = ((const float4*)(a0p + kk + 32))[0];
            n0h = ((const float4*)(a0p + kk + 32))[1];
            n1l = ((const float4*)(a1p + kk + 32))[0];
            n1h = ((const float4*)(a1p + kk + 32))[1];
        }

        // convert current A to bf16 frags
        U8 u0, u1;
        u0.h[0] = __float22bfloat162_rn(make_float2(c0l.x, c0l.y));
        u0.h[1] = __float22bfloat162_rn(make_float2(c0l.z, c0l.w));
        u0.h[2] = __float22bfloat162_rn(make_float2(c0h.x, c0h.y));
        u0.h[3] = __float22bfloat162_rn(make_float2(c0h.z, c0h.w));
        u1.h[0] = __float22bfloat162_rn(make_float2(c1l.x, c1l.y));
        u1.h[1] = __float22bfloat162_rn(make_float2(c1l.z, c1l.w));
        u1.h[2] = __float22bfloat162_rn(make_float2(c1h.x, c1h.y));
        u1.h[3] = __float22bfloat162_rn(make_float2(c1h.z, c1h.w));
        short8 a0 = u0.v, a1 = u1.v;

#pragma unroll
        for (int ni = 0; ni < 8; ++ni) {
            acc[0][ni] = __builtin_amdgcn_mfma_f32_16x16x32_bf16(a0, bf[ni], acc[0][ni], 0, 0, 0);
            acc[1][ni] = __builtin_amdgcn_mfma_f32_16x16x32_bf16(a1, bf[ni], acc[1][ni], 0, 0, 0);
        }

        c0l = n0l; c0h = n0h; c1l = n1l; c1h = n1h;
    }

    float bias[8];
#pragma unroll
    for (int ni = 0; ni < 8; ++ni) bias[ni] = b1[ni * 16 + m];

#pragma unroll
    for (int mi = 0; mi < 2; ++mi)
#pragma unroll
        for (int r = 0; r < 4; ++r) {
            int row = row0 + mi * 16 + q * 4 + r;
            unsigned short* dst = h0b + (size_t)row * HID_F;
#pragma unroll
            for (int ni = 0; ni < 8; ++ni)
                dst[ni * 16 + m] = f2bf(acc[mi][ni][r] + bias[ni]);
        }
}

// ---------------- GEMM2 via MFMA: h2 = h1r @ w2 + b2 ------------------------
// A is already bf16 (h1r) -> direct short8 loads, no conversion. w2t 16 KB L2.
__global__ __launch_bounds__(256) void gemm2_mfma_kernel(
    const unsigned short* __restrict__ h1r, const unsigned short* __restrict__ w2t,
    const float* __restrict__ b2, float* __restrict__ h2)
{
    const int lane = threadIdx.x & 63;
    const int wid  = blockIdx.x * 4 + (threadIdx.x >> 6);
    if (wid >= N_WAVES_G) return;
    const int row0 = wid * 32;
    const int m = lane & 15;
    const int q = lane >> 4;

    f32x4 acc[2][4];
#pragma unroll
    for (int mi = 0; mi < 2; ++mi)
#pragma unroll
        for (int ni = 0; ni < 4; ++ni)
            acc[mi][ni] = (f32x4){0.f, 0.f, 0.f, 0.f};

    const unsigned short* a0p = h1r + (size_t)(row0 + m)      * HID_F + q * 8;
    const unsigned short* a1p = h1r + (size_t)(row0 + 16 + m) * HID_F + q * 8;
    const unsigned short* bp  = w2t + (size_t)m * HID_F + q * 8;

#pragma unroll
    for (int t = 0; t < 4; ++t) {          // kk = t*32, fully unrolled
        short8 a0 = *(const short8*)(a0p + t * 32);
        short8 a1 = *(const short8*)(a1p + t * 32);
#pragma unroll
        for (int ni = 0; ni < 4; ++ni) {
            short8 b = *(const short8*)(bp + (size_t)ni * 16 * HID_F + t * 32);
            acc[0][ni] = __builtin_amdgcn_mfma_f32_16x16x32_bf16(a0, b, acc[0][ni], 0, 0, 0);
            acc[1][ni] = __builtin_amdgcn_mfma_f32_16x16x32_bf16(a1, b, acc[1][ni], 0, 0, 0);
        }
    }

    float bias[4];
#pragma unroll
    for (int ni = 0; ni < 4; ++ni) bias[ni] = b2[ni * 16 + m];

#pragma unroll
    for (int mi = 0; mi < 2; ++mi)
#pragma unroll
        for (int r = 0; r < 4; ++r) {
            int row = row0 + mi * 16 + q * 4 + r;
            float* dst = h2 + (size_t)row * N_CLS;
#pragma unroll
            for (int ni = 0; ni < 4; ++ni)
                dst[ni * 16 + m] = acc[mi][ni][r] + bias[ni];
        }
}

// ---------------- SpMM1 gather: h1r = bf16(relu(sum val*h0b[col])) ----------
__global__ __launch_bounds__(256) void spmm_g128_kernel(
    const int* __restrict__ rp, const int2* __restrict__ es,
    const unsigned short* __restrict__ src, unsigned short* __restrict__ dst)
{
    const int r = blockIdx.x * 4 + threadIdx.y;
    if (r >= N_NODES) return;
    const int lane = threadIdx.x;
    const int j0 = rp[r], j1 = rp[r + 1];

    float ax = 0.f, ay = 0.f;
    int j = j0;
    for (; j + 7 < j1; j += 8) {        // 8 gathers in flight
        int2 e[8];
        ushort2 u[8];
#pragma unroll
        for (int t = 0; t < 8; ++t) e[t] = es[j + t];
#pragma unroll
        for (int t = 0; t < 8; ++t)
            u[t] = ((const ushort2*)(src + (size_t)e[t].x * HID_F))[lane];
#pragma unroll
        for (int t = 0; t < 8; ++t) {
            float v = __int_as_float(e[t].y);
            ax += v * bf2f(u[t].x);
            ay += v * bf2f(u[t].y);
        }
    }
    if (j + 3 < j1) {
        int2 e[4];
        ushort2 u[4];
#pragma unroll
        for (int t = 0; t < 4; ++t) e[t] = es[j + t];
#pragma unroll
        for (int t = 0; t < 4; ++t)
            u[t] = ((const ushort2*)(src + (size_t)e[t].x * HID_F))[lane];
#pragma unroll
        for (int t = 0; t < 4; ++t) {
            float v = __int_as_float(e[t].y);
            ax += v * bf2f(u[t].x);
            ay += v * bf2f(u[t].y);
        }
        j += 4;
    }
    for (; j < j1; ++j) {
        int2 e = es[j];
        float v = __int_as_float(e.y);
        ushort2 u = ((const ushort2*)(src + (size_t)e.x * HID_F))[lane];
        ax += v * bf2f(u.x);
        ay += v * bf2f(u.y);
    }
    ushort2 o;
    o.x = f2bf(fmaxf(ax, 0.f));
    o.y = f2bf(fmaxf(ay, 0.f));
    ((ushort2*)(dst + (size_t)r * HID_F))[lane] = o;
}

// ---------------- SpMM2 gather (F=64) ----------------
__global__ __launch_bounds__(256) void spmm_g64_kernel(
    const int* __restrict__ rp, const int2* __restrict__ es,
    const float* __restrict__ src, float* __restrict__ dst)
{
    const int r = blockIdx.x * 4 + threadIdx.y;
    if (r >= N_NODES) return;
    const int lane = threadIdx.x;
    const int j0 = rp[r], j1 = rp[r + 1];

    float acc = 0.f;
    int j = j0;
    for (; j + 7 < j1; j += 8) {
        int2 e[8];
        float a[8];
#pragma unroll
        for (int t = 0; t < 8; ++t) e[t] = es[j + t];
#pragma unroll
        for (int t = 0; t < 8; ++t)
            a[t] = src[(size_t)e[t].x * N_CLS + lane];
#pragma unroll
        for (int t = 0; t < 8; ++t)
            acc += __int_as_float(e[t].y) * a[t];
    }
    if (j + 3 < j1) {
        int2 e[4];
        float a[4];
#pragma unroll
        for (int t = 0; t < 4; ++t) e[t] = es[j + t];
#pragma unroll
        for (int t = 0; t < 4; ++t)
            a[t] = src[(size_t)e[t].x * N_CLS + lane];
#pragma unroll
        for (int t = 0; t < 4; ++t)
            acc += __int_as_float(e[t].y) * a[t];
        j += 4;
    }
    for (; j < j1; ++j) {
        int2 e = es[j];
        acc += __int_as_float(e.y) * src[(size_t)e.x * N_CLS + lane];
    }
    dst[(size_t)r * N_CLS + lane] = acc;
}

extern "C" void kernel_launch(void* const* d_in, const int* in_sizes, int n_in,
                              void* d_out, int out_size, void* d_ws, size_t ws_size,
                              hipStream_t stream)
{
    const float* x       = (const float*)d_in[0];
    const int*   adj_row = (const int*)  d_in[1];
    const int*   adj_col = (const int*)  d_in[2];
    const float* adj_val = (const float*)d_in[3];
    const float* w1      = (const float*)d_in[4];
    const float* b1      = (const float*)d_in[5];
    const float* w2      = (const float*)d_in[6];
    const float* b2      = (const float*)d_in[7];
    float*       out     = (float*)d_out;

    // workspace carve-up
    char* ws = (char*)d_ws;
    unsigned short* h0b   = (unsigned short*)ws;                  // 25.6 MB
    unsigned short* h1r   = (unsigned short*)(ws + 25600000);     // 25.6 MB
    float*          h2    = (float*)(ws + 51200000);              // 25.6 MB
    int2*           es    = (int2*) (ws + 76800000);              // 12.8 MB
    int*            rp    = (int*)  (ws + 89600000);              // 400 KB + 4
    int*            cur   = (int*)  (ws + 90000016);              // 400 KB
    unsigned short* w1t   = (unsigned short*)(ws + 90400016);     // 128 KB
    int*            lex   = (int*)  (ws + 90531088);              // 400 KB
    int*            bsum  = (int*)  (ws + 90931088);              // ~1.6 KB
    unsigned short* w2t   = (unsigned short*)(ws + 90932656);     // 16 KB

    // ---- prep ----
    w1t_kernel<<<IN_F * HID_F / 256, 256, 0, stream>>>(w1, w1t);
    w2t_kernel<<<HID_F * N_CLS / 256, 256, 0, stream>>>(w2, w2t);
    zero_int_kernel<<<(N_NODES + 255) / 256, 256, 0, stream>>>(cur, N_NODES);
    hist_kernel<<<(N_EDGES + 255) / 256, 256, 0, stream>>>(adj_row, cur);
    scanA_kernel<<<N_SCAN_BLOCKS, SCAN_BLOCK, 0, stream>>>(cur, lex, bsum);
    scanB_kernel<<<1, 512, 0, stream>>>(bsum);
    scanC_kernel<<<N_SCAN_BLOCKS, SCAN_BLOCK, 0, stream>>>(lex, bsum, rp, cur);
    scatter_kernel<<<(N_EDGES + 255) / 256, 256, 0, stream>>>(
        adj_row, adj_col, adj_val, cur, es);

    // ---- conv1 ----
    gemm1_mfma_kernel<<<(N_WAVES_G + 3) / 4, 256, 0, stream>>>(x, w1t, b1, h0b);
    spmm_g128_kernel<<<(N_NODES + 3) / 4, dim3(64, 4), 0, stream>>>(
        rp, es, h0b, h1r);

    // ---- conv2 ----
    gemm2_mfma_kernel<<<(N_WAVES_G + 3) / 4, 256, 0, stream>>>(h1r, w2t, b2, h2);
    spmm_g64_kernel<<<(N_NODES + 3) / 4, dim3(64, 4), 0, stream>>>(
        rp, es, h2, out);
}